// Round 1
// baseline (69.169 us; speedup 1.0000x reference)
//
#include <hip/hip_runtime.h>

// B=32, T=4096, F=16, L=2047, n=8192, 256 output freqs.
// Math: s[b,t] = sum_f x[b,t,f]; r[b,tau] = sum_t s[t]*s[t+tau] (tau=0..2048)
// G[b,m] = (A[m]/16384) * exp(-2*pi*i*2047*m/4096),
// A[m] = r[0] + 2*sum_{j=1}^{2047} r[j]*cos(2*pi*m*j/4096) + (-1)^m r[2048].
// Output layout (verified R3): PLANAR — Re at [b*256+m], Im at [8192+b*256+m].
// R8/R9: fixed ~27us graph + ~41us ws fill; only kernel duration matters.
// R11 (this round): kautoc moved from fp32 VALU (157 TF pipe, ~3.8us) to
// f16 hi/lo-split MFMA (v_mfma_f32_32x32x16_f16, 3 products hi*hi+hi*lo+lo*hi,
// fp32 accum; ~22-bit effective mantissa). Mapping: A[m,k]=s[t0-32m+k],
// B[k,n]=s[t0+tau0+n+k] -> C[m,n] += partial r[tau0+32m+n], tau0 in {0,1024},
// t0 = tstart+16j. Window W[h]=s[tstart-992+h], h in [0,2304), zero-padded:
// out-of-range t contributes exactly 0 (linear autocorr). B's per-lane unit
// offset handled by even/odd dword-pair arrays (4-B-aligned ds_read2_b32);
// A's -64B/lane stride handled by XOR swizzle h^=((h>>5)&7)<<3 (conflict-free).

#define B_DIM 32
#define T_DIM 4096
#define NCHUNK 16
#define TS 256
#define PSTRIDE 2052                   // partial row stride (16B-aligned)
#define THETA 1.5339807878856412e-03f  // 2*pi/4096

typedef _Float16 f16x8 __attribute__((ext_vector_type(8)));
typedef float f32x16 __attribute__((ext_vector_type(16)));
typedef unsigned int u32;
typedef unsigned short u16;
typedef u32 u32x4 __attribute__((ext_vector_type(4)));

static __device__ __forceinline__ u32 packh(_Float16 a, _Float16 b) {
    u32 ua = (u32)__builtin_bit_cast(u16, a);
    u32 ub = (u32)__builtin_bit_cast(u16, b);
    return ua | (ub << 16);
}

// 4 consecutive dwords (only 4-B alignment provable -> ds_read2_b32 pairs)
static __device__ __forceinline__ f16x8 ldb4(const u32* __restrict__ p, int wb) {
    u32x4 d;
    d[0] = p[wb]; d[1] = p[wb + 1]; d[2] = p[wb + 2]; d[3] = p[wb + 3];
    return __builtin_bit_cast(f16x8, d);
}

// ---------------- K1: s[b,t] = sum_f x[b,t,f] ----------------
__global__ __launch_bounds__(256) void ksum(const float* __restrict__ x,
                                            float* __restrict__ s) {
    int i = blockIdx.x * 256 + threadIdx.x;          // 0..131071 = b*4096+t
    const float4* xv = (const float4*)(x + (size_t)i * 16);
    float4 a = xv[0], b = xv[1], c = xv[2], d = xv[3];
    s[i] = ((a.x + a.y) + (a.z + a.w)) + ((b.x + b.y) + (b.z + b.w)) +
           ((c.x + c.y) + (c.z + c.w)) + ((d.x + d.y) + (d.z + d.w));
}

// ---------------- K2: MFMA f16-split autocorr ----------------
// grid (32,16); 256 thr = 4 waves. Wave w owns t0 = tstart+16j, j in [4w,4w+4).
// Each wave: 4 j-steps x {2 tau-tiles x 3 split-MFMAs} = 24 MFMAs.
// Cross-wave 4-way merge in LDS; wave 0 writes the partial row.
__global__ __launch_bounds__(256) void kautoc(const float* __restrict__ s,
                                              float* __restrict__ part) {
    __shared__ __align__(16) _Float16 Ahi[1280];   // A-region h in [0,1248), XOR-swizzled
    __shared__ __align__(16) _Float16 Alo[1280];
    __shared__ __align__(16) u32 BevHi[664];       // B-region h in [992,2304), dword pairs
    __shared__ __align__(16) u32 BodHi[664];       //   Bod pre-shifted by one half
    __shared__ __align__(16) u32 BevLo[664];
    __shared__ __align__(16) u32 BodLo[664];
    __shared__ float mbuf[6144];                   // 3 waves x 2 tiles x 1024

    int tid = threadIdx.x;
    int b = blockIdx.x;
    int q = blockIdx.y;
    int tstart = q * TS;
    const float* sb = s + (size_t)b * T_DIM;

    // ---- stage: W[h] = s[tstart-992+h], h in [0,2304), split hi/lo fp16 ----
    for (int g = tid; g < 288; g += 256) {
        int h0 = g << 3;
        int t0 = tstart - 992 + h0;
        float f[9];
        if (t0 >= 0 && t0 + 8 < T_DIM) {
            float4 v0 = *(const float4*)&sb[t0];
            float4 v1 = *(const float4*)&sb[t0 + 4];
            f[0] = v0.x; f[1] = v0.y; f[2] = v0.z; f[3] = v0.w;
            f[4] = v1.x; f[5] = v1.y; f[6] = v1.z; f[7] = v1.w;
            f[8] = sb[t0 + 8];
        } else {
            #pragma unroll
            for (int i = 0; i < 9; ++i) {
                int t = t0 + i;
                f[i] = (t >= 0 && t < T_DIM) ? sb[t] : 0.f;
            }
        }
        _Float16 hi[9], lo[9];
        #pragma unroll
        for (int i = 0; i < 9; ++i) {
            hi[i] = (_Float16)f[i];
            lo[i] = (_Float16)(f[i] - (float)hi[i]);
        }
        if (h0 < 1248) {                           // A-region (swizzled groups)
            int sa = h0 ^ (((h0 >> 5) & 7) << 3);
            f16x8 vh, vl;
            #pragma unroll
            for (int r = 0; r < 8; ++r) { vh[r] = hi[r]; vl[r] = lo[r]; }
            *(f16x8*)&Ahi[sa] = vh;
            *(f16x8*)&Alo[sa] = vl;
        }
        if (h0 >= 992) {                           // B-region (ev/od dword pairs)
            int wb = (h0 - 992) >> 1;              // multiple of 4 -> b128 writes
            u32x4 evh, odh, evl, odl;
            evh[0] = packh(hi[0], hi[1]); evh[1] = packh(hi[2], hi[3]);
            evh[2] = packh(hi[4], hi[5]); evh[3] = packh(hi[6], hi[7]);
            odh[0] = packh(hi[1], hi[2]); odh[1] = packh(hi[3], hi[4]);
            odh[2] = packh(hi[5], hi[6]); odh[3] = packh(hi[7], hi[8]);
            evl[0] = packh(lo[0], lo[1]); evl[1] = packh(lo[2], lo[3]);
            evl[2] = packh(lo[4], lo[5]); evl[3] = packh(lo[6], lo[7]);
            odl[0] = packh(lo[1], lo[2]); odl[1] = packh(lo[3], lo[4]);
            odl[2] = packh(lo[5], lo[6]); odl[3] = packh(lo[7], lo[8]);
            *(u32x4*)&BevHi[wb] = evh; *(u32x4*)&BodHi[wb] = odh;
            *(u32x4*)&BevLo[wb] = evl; *(u32x4*)&BodLo[wb] = odl;
        }
    }
    __syncthreads();

    int lane = tid & 63;
    int w = tid >> 6;                              // wave id, uniform
    int nn = lane & 31;                            // A row m / B col n
    int kb = (lane >> 5) << 3;                     // k-base 0 or 8
    int amBase = 992 - (nn << 5) + kb;             // A frag offset (add 16j)
    const u32* bptrH = (nn & 1) ? BodHi : BevHi;   // parity loop-invariant
    const u32* bptrL = (nn & 1) ? BodLo : BevLo;

    f32x16 acc0, acc1;
    #pragma unroll
    for (int i = 0; i < 16; ++i) { acc0[i] = 0.f; acc1[i] = 0.f; }

    #pragma unroll
    for (int jj = 0; jj < 4; ++jj) {
        int j = (w << 2) + jj;                     // t0 = tstart + 16j
        int aoff = amBase + (j << 4);              // 8-aligned, in [0,1241)
        int sa = aoff ^ (((aoff >> 5) & 7) << 3);  // conflict-free swizzle
        f16x8 aH = *(const f16x8*)&Ahi[sa];
        f16x8 aL = *(const f16x8*)&Alo[sa];
        int w0 = ((j << 4) + nn + kb) >> 1;        // tau0=0 frag dword base
        int w1 = w0 + 512;                         // tau0=1024
        f16x8 b0H = ldb4(bptrH, w0);
        f16x8 b0L = ldb4(bptrL, w0);
        f16x8 b1H = ldb4(bptrH, w1);
        f16x8 b1L = ldb4(bptrL, w1);
        // interleave acc0/acc1 chains to cover MFMA latency
        acc0 = __builtin_amdgcn_mfma_f32_32x32x16_f16(aH, b0H, acc0, 0, 0, 0);
        acc1 = __builtin_amdgcn_mfma_f32_32x32x16_f16(aH, b1H, acc1, 0, 0, 0);
        acc0 = __builtin_amdgcn_mfma_f32_32x32x16_f16(aH, b0L, acc0, 0, 0, 0);
        acc1 = __builtin_amdgcn_mfma_f32_32x32x16_f16(aH, b1L, acc1, 0, 0, 0);
        acc0 = __builtin_amdgcn_mfma_f32_32x32x16_f16(aL, b0H, acc0, 0, 0, 0);
        acc1 = __builtin_amdgcn_mfma_f32_32x32x16_f16(aL, b1H, acc1, 0, 0, 0);
    }

    // ---- lag 2048: t in [tstart-992, tstart-992+256), reads staged window ----
    float a2 = 0.f;
    if (w == 3) {
        #pragma unroll
        for (int u = 0; u < 4; ++u) {
            int e1 = (u << 6) + lane;              // [0,256) -> A-region
            int s1 = e1 ^ (((e1 >> 5) & 7) << 3);
            float v1 = (float)Ahi[s1] + (float)Alo[s1];
            int hb = e1 + 1056;                    // (e1+2048)-992 -> B-region
            u32 dH = BevHi[hb >> 1];
            u32 dL = BevLo[hb >> 1];
            u16 uh = (hb & 1) ? (u16)(dH >> 16) : (u16)dH;
            u16 ul = (hb & 1) ? (u16)(dL >> 16) : (u16)dL;
            float v2 = (float)__builtin_bit_cast(_Float16, uh)
                     + (float)__builtin_bit_cast(_Float16, ul);
            a2 = fmaf(v1, v2, a2);
        }
        #pragma unroll
        for (int off = 32; off; off >>= 1) a2 += __shfl_down(a2, off, 64);
    }

    // ---- 4-way cross-wave merge (mbuf disjoint from A/B arrays) ----
    if (w > 0) {
        float* mb = mbuf + ((w - 1) << 11);
        #pragma unroll
        for (int g = 0; g < 16; ++g) {
            mb[(g << 6) + lane] = acc0[g];
            mb[1024 + (g << 6) + lane] = acc1[g];
        }
    }
    __syncthreads();

    float* pr = part + ((size_t)b * NCHUNK + q) * PSTRIDE;
    if (w == 0) {
        #pragma unroll
        for (int g = 0; g < 16; ++g) {
            int idx = (g << 6) + lane;
            float v0 = acc0[g] + mbuf[idx] + mbuf[2048 + idx] + mbuf[4096 + idx];
            float v1 = acc1[g] + mbuf[1024 + idx] + mbuf[3072 + idx] + mbuf[5120 + idx];
            // C/D layout (m101): col=lane&31, row=(g&3)+8*(g>>2)+4*(lane>>5)
            int mm = (g & 3) + ((g >> 2) << 3) + ((lane >> 5) << 2);
            int lag = (mm << 5) + nn;              // tau0 + 32m + n
            pr[lag] = v0;
            pr[1024 + lag] = v1;
        }
    }
    if (tid == 192) pr[2048] = a2;                 // w==3, lane 0
}

// ---------------- K3: reduce + folded cosine DFT (unchanged) ----------------
__global__ __launch_bounds__(256) void kdft(const float* __restrict__ part,
                                            float* __restrict__ out) {
    __shared__ float lr[PSTRIDE];
    __shared__ float se[1026];
    __shared__ float sd[1026];
    int b = blockIdx.x;
    int tid = threadIdx.x;
    const float* pb = part + (size_t)b * NCHUNK * PSTRIDE;
    for (int idx = tid; idx < 513; idx += 256) {
        float4 acc = make_float4(0.f, 0.f, 0.f, 0.f);
        #pragma unroll
        for (int q = 0; q < NCHUNK; ++q) {
            float4 v = *(const float4*)&pb[(size_t)q * PSTRIDE + idx * 4];
            acc.x += v.x; acc.y += v.y; acc.z += v.z; acc.w += v.w;
        }
        *(float4*)&lr[idx * 4] = acc;
    }
    __syncthreads();
    for (int j = 1 + tid; j < 1024; j += 256) {
        float a = lr[j], c = lr[2048 - j];
        se[j] = a + c;
        sd[j] = a - c;
    }
    if (tid == 0) { se[1024] = 0.f; sd[1024] = 0.f; }
    __syncthreads();

    int m = blockIdx.y * 32 + (tid >> 3);
    int slice = tid & 7;
    const float* arr = (m & 1) ? sd : se;
    float ps = 0.0f;
    #pragma unroll 8
    for (int k = 0; k < 128; ++k) {
        int j = 1 + slice + (k << 3);
        int p = (m * j) & 4095;
        ps = fmaf(arr[j], __cosf((float)p * THETA), ps);
    }
    #pragma unroll
    for (int off = 4; off; off >>= 1) ps += __shfl_down(ps, off, 8);
    if (slice == 0) {
        float A;
        if (m & 1) {
            A = 2.0f * ps + lr[0] - lr[2048];
        } else {
            float sgn = ((m >> 1) & 1) ? -2.0f : 2.0f;
            A = 2.0f * ps + lr[0] + lr[2048] + sgn * lr[1024];
        }
        int qp = (2047 * m) & 4095;
        float ang = (float)qp * THETA;
        float gg = A * (1.0f / 16384.0f);
        out[(size_t)b * 256 + m] = gg * __cosf(ang);
        out[8192 + (size_t)b * 256 + m] = -gg * __sinf(ang);
    }
}

extern "C" void kernel_launch(void* const* d_in, const int* in_sizes, int n_in,
                              void* d_out, int out_size, void* d_ws, size_t ws_size,
                              hipStream_t stream) {
    const float* x = (const float*)d_in[0];
    float* out = (float*)d_out;
    float* s = (float*)d_ws;                          // 32*4096 floats (512 KB)
    float* part = s + B_DIM * T_DIM;                  // 32*16*2052 floats (4.2 MB)
    ksum<<<dim3(512), dim3(256), 0, stream>>>(x, s);
    kautoc<<<dim3(B_DIM, NCHUNK), dim3(256), 0, stream>>>(s, part);
    kdft<<<dim3(B_DIM, 8), dim3(256), 0, stream>>>(part, out);
}